// Round 21
// baseline (34.716 us; speedup 1.0000x reference)
//
#include <hip/hip_runtime.h>

#define F_ALPHA 0.25f
#define F_EPS   1e-8f
#define NB 4     // preds per block-group
#define NGRP 2   // pred-groups per block (persistent-style)

// R16 body (best: 31.4us) + half grid, 2 sequential pred-groups per block:
// 1800 blocks all co-resident (capacity ~2048) -> no ragged second cohort,
// halved wave-spawn. Barrier between groups protects fclsT reuse.
__global__ void __launch_bounds__(256, 4)
fused_cost_kernel(const float* __restrict__ logits,      // [N, C]
                  const float4* __restrict__ pred_boxes, // [N]
                  const float4* __restrict__ tgt_boxes,  // [T]
                  const int* __restrict__ tgt_ids,       // [T]
                  float* __restrict__ out,               // [N, T]
                  int N, int C, int T, int nblocks) {
    __shared__ float4 fclsT[96];                         // [class] -> NB costs
    const int tid = threadIdx.x;

    for (int g = 0; g < NGRP; ++g) {
        const int n0 = (blockIdx.x + g * nblocks) * NB;
        if (g) __syncthreads();                          // fclsT reuse hazard

        // ---- phase 1: wave w computes pred (n0+w)'s focal row, transposed ----
        {
            const int w = tid >> 6, l = tid & 63;
            const float* lrow = logits + (size_t)(n0 + w) * C;
            for (int c = l; c < C; c += 64) {
                float x = lrow[c];
                float p = 1.0f / (1.0f + expf(-x));
                float om = 1.0f - p;
                float pos = F_ALPHA * om * om * (-logf(p + F_EPS));
                float neg = (1.0f - F_ALPHA) * p * p * (-logf(om + F_EPS));
                ((float*)fclsT)[c * NB + w] = 2.0f * (pos - neg) + 2.0f;
            }
        }

        // pred-side params (block-uniform)
        float pcx[NB], pcy[NB], pw_[NB], ph_[NB];
        float px1[NB], py1[NB], px2[NB], py2[NB], parea[NB];
        float* op[NB];
#pragma unroll
        for (int i = 0; i < NB; ++i) {
            const int n = n0 + i;                        // N % (NB*NGRP) == 0
            float4 pb = pred_boxes[n];
            pcx[i] = pb.x; pcy[i] = pb.y; pw_[i] = pb.z; ph_[i] = pb.w;
            px1[i] = fmaf(-0.5f, pb.z, pb.x);  py1[i] = fmaf(-0.5f, pb.w, pb.y);
            px2[i] = fmaf( 0.5f, pb.z, pb.x);  py2[i] = fmaf( 0.5f, pb.w, pb.y);
            parea[i] = pb.z * pb.w;
            op[i] = out + (size_t)n * T;
        }
        __syncthreads();

        auto body = [&](int t) {
            float4 tb = tgt_boxes[t];                    // unit-stride float4
            int id = tgt_ids[t];                         // unit-stride dword
            float4 cls4 = fclsT[id];                     // one ds_read_b128
            const float clsv[NB] = {cls4.x, cls4.y, cls4.z, cls4.w};

            float tx1 = fmaf(-0.5f, tb.z, tb.x), ty1 = fmaf(-0.5f, tb.w, tb.y);
            float tx2 = fmaf( 0.5f, tb.z, tb.x), ty2 = fmaf( 0.5f, tb.w, tb.y);
            float tarea = tb.z * tb.w;

#pragma unroll
            for (int i = 0; i < NB; ++i) {
                float ax = fmaxf(px1[i], tx1), bx = fminf(px2[i], tx2);
                float ay = fmaxf(py1[i], ty1), by = fminf(py2[i], ty2);
                float dx = bx - ax, dy = by - ay;
                float iw = fmaxf(dx, 0.0f), ih = fmaxf(dy, 0.0f);
                float inter = iw * ih;
                float uni = (parea[i] + tarea) - inter;

                float ew = (pw_[i] + tb.z) - dx;         // enclosing identity
                float eh = (ph_[i] + tb.w) - dy;
                float earea = ew * eh;

                float l1 = (fabsf(pcx[i] - tb.x) + fabsf(pcy[i] - tb.y))
                         + (fabsf(pw_[i] - tb.z) + fabsf(ph_[i] - tb.w));

                float den = uni * earea;
                float r   = __builtin_amdgcn_rcpf(den);
                float num = fmaf(uni, uni, inter * earea);

                float v = fmaf(5.0f, l1, clsv[i]);       // 5*l1 + 2*cls + 2
                v = fmaf(-2.0f, num * r, v);
                op[i][t] = v;                            // coalesced dword store
            }
        };

        // ---- phase 2: unroll-4 target sweep ----
        int t = tid;
        for (; t + 768 < T; t += 1024) {
            body(t); body(t + 256); body(t + 512); body(t + 768);
        }
        for (; t < T; t += 256) body(t);
    }
}

extern "C" void kernel_launch(void* const* d_in, const int* in_sizes, int n_in,
                              void* d_out, int out_size, void* d_ws, size_t ws_size,
                              hipStream_t stream) {
    const float* logits = (const float*)d_in[0];   // [bs, Q, C]
    const float* pboxes = (const float*)d_in[1];   // [bs, Q, 4]
    const float* tboxes = (const float*)d_in[2];   // [T, 4]
    const int*   tids   = (const int*)d_in[3];     // [T]

    int N = in_sizes[1] / 4;          // bs*Q = 14400
    int C = in_sizes[0] / N;          // 91
    int T = in_sizes[2] / 4;          // 1600

    int nblocks = N / (NB * NGRP);    // 1800 — all co-resident
    fused_cost_kernel<<<nblocks, 256, 0, stream>>>(
        logits, (const float4*)pboxes, (const float4*)tboxes, tids,
        (float*)d_out, N, C, T, nblocks);
}

// Round 22
// 30.478 us; speedup vs baseline: 1.1390x; 1.1390x over previous
//
#include <hip/hip_runtime.h>

#define F_ALPHA 0.25f
#define F_EPS   1e-8f
#define NB 4   // preds per block

// R16 structure + min3 reformulation:
// extent dx = min(pw, tw, 0.5*(pw+tw) - |pcx-tcx|)  [exact identity]
// -> no xyxy conversion at all; |D| shared with L1; v_min3_f32 fusion.
__global__ void __launch_bounds__(256, 4)
fused_cost_kernel(const float* __restrict__ logits,      // [N, C]
                  const float4* __restrict__ pred_boxes, // [N]
                  const float4* __restrict__ tgt_boxes,  // [T]
                  const int* __restrict__ tgt_ids,       // [T]
                  float* __restrict__ out,               // [N, T]
                  int N, int C, int T) {
    __shared__ float4 fclsT[96];                         // [class] -> NB costs
    const int n0  = blockIdx.x * NB;
    const int tid = threadIdx.x;

    // ---- phase 1: wave w computes pred (n0+w)'s focal row, transposed ----
    {
        const int w = tid >> 6, l = tid & 63;
        const float* lrow = logits + (size_t)(n0 + w) * C;
        for (int c = l; c < C; c += 64) {
            float x = lrow[c];
            float p = 1.0f / (1.0f + expf(-x));
            float om = 1.0f - p;
            float pos = F_ALPHA * om * om * (-logf(p + F_EPS));
            float neg = (1.0f - F_ALPHA) * p * p * (-logf(om + F_EPS));
            ((float*)fclsT)[c * NB + w] = 2.0f * (pos - neg) + 2.0f; // 2*cls+2
        }
    }

    // pred-side params (block-uniform): just 5 scalars + pointer per pred
    float pcx[NB], pcy[NB], pw_[NB], ph_[NB], parea[NB];
    float* op[NB];
#pragma unroll
    for (int i = 0; i < NB; ++i) {
        const int n = n0 + i;                            // N % NB == 0
        float4 pb = pred_boxes[n];
        pcx[i] = pb.x; pcy[i] = pb.y; pw_[i] = pb.z; ph_[i] = pb.w;
        parea[i] = pb.z * pb.w;
        op[i] = out + (size_t)n * T;
    }
    __syncthreads();

    auto body = [&](int t) {
        float4 tb = tgt_boxes[t];                        // unit-stride float4
        int id = tgt_ids[t];                             // unit-stride dword
        float4 cls4 = fclsT[id];                         // one ds_read_b128
        const float clsv[NB] = {cls4.x, cls4.y, cls4.z, cls4.w};
        float tarea = tb.z * tb.w;

#pragma unroll
        for (int i = 0; i < NB; ++i) {
            float Dx = pcx[i] - tb.x, Dy = pcy[i] - tb.y;
            float Wx = pw_[i] + tb.z, Wy = ph_[i] + tb.w;

            // overlap extents via identity (no xyxy corners needed)
            float gx = fmaf(0.5f, Wx, -fabsf(Dx));
            float gy = fmaf(0.5f, Wy, -fabsf(Dy));
            float dx = fminf(fminf(pw_[i], tb.z), gx);   // v_min3_f32
            float dy = fminf(fminf(ph_[i], tb.w), gy);   // v_min3_f32

            float iw = fmaxf(dx, 0.0f), ih = fmaxf(dy, 0.0f);
            float inter = iw * ih;
            float uni = (parea[i] + tarea) - inter;

            float ew = Wx - dx, eh = Wy - dy;            // enclosing extents
            float earea = ew * eh;

            float sx = pw_[i] - tb.z, sy = ph_[i] - tb.w;
            float l1 = (fabsf(Dx) + fabsf(Dy)) + (fabsf(sx) + fabsf(sy));

            // 2*inter/uni + 2*uni/earea = 2*(inter*earea + uni^2)*rcp(uni*earea)
            float den = uni * earea;
            float r   = __builtin_amdgcn_rcpf(den);
            float num = fmaf(uni, uni, inter * earea);

            float v = fmaf(5.0f, l1, clsv[i]);           // 5*l1 + 2*cls + 2
            v = fmaf(-2.0f, num * r, v);
            op[i][t] = v;                                // coalesced dword store
        }
    };

    // ---- phase 2: unroll-4 target sweep (R16 best) ----
    int t = tid;
    for (; t + 768 < T; t += 1024) {
        body(t); body(t + 256); body(t + 512); body(t + 768);
    }
    for (; t < T; t += 256) body(t);
}

extern "C" void kernel_launch(void* const* d_in, const int* in_sizes, int n_in,
                              void* d_out, int out_size, void* d_ws, size_t ws_size,
                              hipStream_t stream) {
    const float* logits = (const float*)d_in[0];   // [bs, Q, C]
    const float* pboxes = (const float*)d_in[1];   // [bs, Q, 4]
    const float* tboxes = (const float*)d_in[2];   // [T, 4]
    const int*   tids   = (const int*)d_in[3];     // [T]

    int N = in_sizes[1] / 4;          // bs*Q = 14400
    int C = in_sizes[0] / N;          // 91
    int T = in_sizes[2] / 4;          // 1600

    int grid = N / NB;                // 3600
    fused_cost_kernel<<<grid, 256, 0, stream>>>(
        logits, (const float4*)pboxes, (const float4*)tboxes, tids,
        (float*)d_out, N, C, T);
}

// Round 23
// 30.360 us; speedup vs baseline: 1.1435x; 1.0039x over previous
//
#include <hip/hip_runtime.h>

#define F_ALPHA 0.25f
#define F_EPS   1e-8f
#define NB 4   // preds per block

// R22 body (best: 30.5us), launch bounds (256,2): 256-VGPR budget so the
// scheduler stops trading ILP/remat for occupancy at unroll-4 pressure.
__global__ void __launch_bounds__(256, 2)
fused_cost_kernel(const float* __restrict__ logits,      // [N, C]
                  const float4* __restrict__ pred_boxes, // [N]
                  const float4* __restrict__ tgt_boxes,  // [T]
                  const int* __restrict__ tgt_ids,       // [T]
                  float* __restrict__ out,               // [N, T]
                  int N, int C, int T) {
    __shared__ float4 fclsT[96];                         // [class] -> NB costs
    const int n0  = blockIdx.x * NB;
    const int tid = threadIdx.x;

    // ---- phase 1: wave w computes pred (n0+w)'s focal row, transposed ----
    {
        const int w = tid >> 6, l = tid & 63;
        const float* lrow = logits + (size_t)(n0 + w) * C;
        for (int c = l; c < C; c += 64) {
            float x = lrow[c];
            float p = 1.0f / (1.0f + expf(-x));
            float om = 1.0f - p;
            float pos = F_ALPHA * om * om * (-logf(p + F_EPS));
            float neg = (1.0f - F_ALPHA) * p * p * (-logf(om + F_EPS));
            ((float*)fclsT)[c * NB + w] = 2.0f * (pos - neg) + 2.0f; // 2*cls+2
        }
    }

    // pred-side params (block-uniform): 5 scalars + pointer per pred
    float pcx[NB], pcy[NB], pw_[NB], ph_[NB], parea[NB];
    float* op[NB];
#pragma unroll
    for (int i = 0; i < NB; ++i) {
        const int n = n0 + i;                            // N % NB == 0
        float4 pb = pred_boxes[n];
        pcx[i] = pb.x; pcy[i] = pb.y; pw_[i] = pb.z; ph_[i] = pb.w;
        parea[i] = pb.z * pb.w;
        op[i] = out + (size_t)n * T;
    }
    __syncthreads();

    auto body = [&](int t) {
        float4 tb = tgt_boxes[t];                        // unit-stride float4
        int id = tgt_ids[t];                             // unit-stride dword
        float4 cls4 = fclsT[id];                         // one ds_read_b128
        const float clsv[NB] = {cls4.x, cls4.y, cls4.z, cls4.w};
        float tarea = tb.z * tb.w;

#pragma unroll
        for (int i = 0; i < NB; ++i) {
            float Dx = pcx[i] - tb.x, Dy = pcy[i] - tb.y;
            float Wx = pw_[i] + tb.z, Wy = ph_[i] + tb.w;

            // overlap extents via identity (no xyxy corners needed)
            float gx = fmaf(0.5f, Wx, -fabsf(Dx));
            float gy = fmaf(0.5f, Wy, -fabsf(Dy));
            float dx = fminf(fminf(pw_[i], tb.z), gx);   // v_min3_f32
            float dy = fminf(fminf(ph_[i], tb.w), gy);   // v_min3_f32

            float iw = fmaxf(dx, 0.0f), ih = fmaxf(dy, 0.0f);
            float inter = iw * ih;
            float uni = (parea[i] + tarea) - inter;

            float ew = Wx - dx, eh = Wy - dy;            // enclosing extents
            float earea = ew * eh;

            float sx = pw_[i] - tb.z, sy = ph_[i] - tb.w;
            float l1 = (fabsf(Dx) + fabsf(Dy)) + (fabsf(sx) + fabsf(sy));

            // 2*inter/uni + 2*uni/earea = 2*(inter*earea + uni^2)*rcp(uni*earea)
            float den = uni * earea;
            float r   = __builtin_amdgcn_rcpf(den);
            float num = fmaf(uni, uni, inter * earea);

            float v = fmaf(5.0f, l1, clsv[i]);           // 5*l1 + 2*cls + 2
            v = fmaf(-2.0f, num * r, v);
            op[i][t] = v;                                // coalesced dword store
        }
    };

    // ---- phase 2: unroll-4 target sweep ----
    int t = tid;
    for (; t + 768 < T; t += 1024) {
        body(t); body(t + 256); body(t + 512); body(t + 768);
    }
    for (; t < T; t += 256) body(t);
}

extern "C" void kernel_launch(void* const* d_in, const int* in_sizes, int n_in,
                              void* d_out, int out_size, void* d_ws, size_t ws_size,
                              hipStream_t stream) {
    const float* logits = (const float*)d_in[0];   // [bs, Q, C]
    const float* pboxes = (const float*)d_in[1];   // [bs, Q, 4]
    const float* tboxes = (const float*)d_in[2];   // [T, 4]
    const int*   tids   = (const int*)d_in[3];     // [T]

    int N = in_sizes[1] / 4;          // bs*Q = 14400
    int C = in_sizes[0] / N;          // 91
    int T = in_sizes[2] / 4;          // 1600

    int grid = N / NB;                // 3600
    fused_cost_kernel<<<grid, 256, 0, stream>>>(
        logits, (const float4*)pboxes, (const float4*)tboxes, tids,
        (float*)d_out, N, C, T);
}